// Round 3
// baseline (74.612 us; speedup 1.0000x reference)
//
#include <hip/hip_runtime.h>
#include <math.h>

// Problem constants (B=16, T=3000, F=201)
constexpr int BB     = 16;
constexpr int T      = 3000;
constexpr int F      = 201;
constexpr int NFFT   = 400;            // 2*(F-1)
constexpr int HOP    = 160;
constexpr int K      = 402;            // 2*F (real/imag interleaved)
constexpr int KP     = 416;            // K padded to multiple of 32
constexpr int JP     = 480;            // padded W rows: j = m + 160*dt, dt=0..2
constexpr int ESTLEN = (T - 1) * HOP + NFFT;   // 480240
constexpr int OUTLEN = ESTLEN - NFFT;          // 479840 per batch
constexpr float EPS  = 1e-12f;

constexpr int UT      = 96;            // u-rows per block (3 waves x 32)
constexpr int AROWS   = 98;            // UT + 2 halo
constexpr int ASTR    = 40;            // shorts per A-LDS row (80B, 16B-aligned chunks)
constexpr int NKS     = 13;            // K-steps of 32
constexpr int WS_HALF = JP * 32;       // shorts per W buffer (30720 B)
constexpr int AS_HALF = AROWS * ASTR;  // shorts per A buffer (7840 B)

typedef short bf16x8 __attribute__((ext_vector_type(8)));
typedef float f32x16 __attribute__((ext_vector_type(16)));

__device__ __forceinline__ unsigned short f2bf(float f) {
    unsigned int u = __float_as_uint(f);
    u = (u + 0x7fffu + ((u >> 16) & 1u)) >> 16;
    return (unsigned short)u;
}

// ---------------- table builders ----------------

// Wt2[j][k] bf16, j in [0,480), k in [0,416). Zero for j>=400 or k>=402.
__global__ void build_wt2(unsigned short* __restrict__ Wt2) {
    int idx = blockIdx.x * blockDim.x + threadIdx.x;
    if (idx >= JP * KP) return;
    int j = idx / KP;
    int k = idx - j * KP;
    float v = 0.f;
    if (j < NFFT && k < K) {
        int f = k >> 1;
        bool is_re = (k & 1) == 0;
        float c = (f == 0 || f == F - 1) ? (1.f / 400.f) : (2.f / 400.f);
        int m = (j * f) % NFFT;
        float ang = (float)(2.0 * M_PI * (double)m / 400.0);
        float tw = is_re ? cosf(ang) : -sinf(ang);
        float win = 0.54f - 0.46f * cosf((float)(2.0 * M_PI * (double)j / 400.0));
        v = c * tw * win;
    }
    Wt2[idx] = f2bf(v);
}

// reciprocal sum-of-squared-window table
__global__ void build_rssw(float* __restrict__ rssw) {
    int p = blockIdx.x * blockDim.x + threadIdx.x;
    if (p >= ESTLEN) return;
    int t_hi = p / HOP; if (t_hi > T - 1) t_hi = T - 1;
    int t_lo = (p >= NFFT) ? ((p - NFFT) / HOP + 1) : 0;
    float s = 0.f;
    for (int t = t_lo; t <= t_hi; ++t) {
        int j = p - t * HOP;
        float w = 0.54f - 0.46f * cosf((float)(2.0 * M_PI * (double)j / 400.0));
        s += w * w;
    }
    rssw[p] = (s > EPS) ? 1.f / s : 1.f;
}

// ---------------- fused MFMA gather-GEMM, 2-phase pipelined ----------------
__global__ __launch_bounds__(192, 2)
void istft_fused(const float* __restrict__ A, const unsigned short* __restrict__ Wt2,
                 const float* __restrict__ rssw, float* __restrict__ out) {
    __shared__ unsigned short Ws[2 * WS_HALF];
    __shared__ unsigned short As[2 * AS_HALF];

    const int tid  = threadIdx.x;
    const int lane = tid & 63;
    const int w    = tid >> 6;          // wave 0..2
    const int lj   = lane & 31;
    const int lh   = lane >> 5;         // 0/1
    const int b    = blockIdx.y;
    const int u0   = 1 + blockIdx.x * UT;
    const int tbase = u0 - 2;           // As row r <-> frame t = tbase + r

    f32x16 acc[5];
    #pragma unroll
    for (int mt = 0; mt < 5; ++mt)
        #pragma unroll
        for (int i = 0; i < 16; ++i) acc[mt][i] = 0.f;

    // A staging map: main item (rows 0..95, 16-float halves), extra (rows 96,97, 8-float octs)
    const int rm = tid >> 1;
    const int hm = tid & 1;
    const int tm = tbase + rm;
    const bool vm = (tm >= 0 && tm < T);
    const float* rowm = A + (size_t)(b * T + tm) * K;
    const bool hasx = (tid < 8);
    const int rx = 96 + (tid >> 2);
    const int ox = tid & 3;
    const int tx = tbase + rx;
    const bool vx = hasx && (tx >= 0 && tx < T);
    const float* rowx = A + (size_t)(b * T + tx) * K;

    auto stage_W = [&](unsigned short* dst, int k0) {
        #pragma unroll
        for (int it = 0; it < 10; ++it) {
            int P  = it * 192 + tid;              // 1920 chunks exactly
            int j  = P >> 2;
            int cp = P & 3;
            int c  = cp ^ ((j >> 1) & 3);         // pre-swizzled source
            const unsigned short* g = Wt2 + (size_t)j * KP + k0 + c * 8;
            unsigned short* l = dst + (size_t)(it * 192 + w * 64) * 8;
            __builtin_amdgcn_global_load_lds(
                (const __attribute__((address_space(1))) void*)g,
                (__attribute__((address_space(3))) void*)l, 16, 0, 0);
        }
    };

    auto load_A = [&](int k0, float* a16, float* a8) {
        int kb = k0 + hm * 16;
        if (vm) {
            if (kb + 16 <= K) {
                #pragma unroll
                for (int q = 0; q < 4; ++q)
                    *reinterpret_cast<float4*>(&a16[q * 4]) =
                        *reinterpret_cast<const float4*>(rowm + kb + q * 4);
            } else {
                #pragma unroll
                for (int i = 0; i < 16; ++i)
                    a16[i] = (kb + i < K) ? rowm[kb + i] : 0.f;
            }
        } else {
            #pragma unroll
            for (int i = 0; i < 16; ++i) a16[i] = 0.f;
        }
        int kx = k0 + ox * 8;
        if (vx) {
            if (kx + 8 <= K) {
                #pragma unroll
                for (int q = 0; q < 2; ++q)
                    *reinterpret_cast<float4*>(&a8[q * 4]) =
                        *reinterpret_cast<const float4*>(rowx + kx + q * 4);
            } else {
                #pragma unroll
                for (int i = 0; i < 8; ++i)
                    a8[i] = (kx + i < K) ? rowx[kx + i] : 0.f;
            }
        } else {
            #pragma unroll
            for (int i = 0; i < 8; ++i) a8[i] = 0.f;
        }
    };

    auto write_A = [&](unsigned short* dst, const float* a16, const float* a8) {
        unsigned short s[16];
        #pragma unroll
        for (int i = 0; i < 16; ++i) s[i] = f2bf(a16[i]);
        *reinterpret_cast<bf16x8*>(&dst[rm * ASTR + hm * 16]) =
            *reinterpret_cast<const bf16x8*>(&s[0]);
        *reinterpret_cast<bf16x8*>(&dst[rm * ASTR + hm * 16 + 8]) =
            *reinterpret_cast<const bf16x8*>(&s[8]);
        if (hasx) {
            unsigned short sx[8];
            #pragma unroll
            for (int i = 0; i < 8; ++i) sx[i] = f2bf(a8[i]);
            *reinterpret_cast<bf16x8*>(&dst[rx * ASTR + ox * 8]) =
                *reinterpret_cast<const bf16x8*>(&sx[0]);
        }
    };

    auto compute = [&](const unsigned short* WsC, const unsigned short* AsC) {
        bf16x8 af[3][2];
        #pragma unroll
        for (int dt = 0; dt < 3; ++dt)
            #pragma unroll
            for (int kh = 0; kh < 2; ++kh)
                af[dt][kh] = *reinterpret_cast<const bf16x8*>(
                    &AsC[(w * 32 + lj + 2 - dt) * ASTR + kh * 16 + lh * 8]);
        #pragma unroll
        for (int dt = 0; dt < 3; ++dt)
            #pragma unroll
            for (int kh = 0; kh < 2; ++kh)
                #pragma unroll
                for (int mt = 0; mt < 5; ++mt) {   // mt innermost: acc reuse distance 5
                    int j = dt * 160 + mt * 32 + lj;
                    int c = (kh * 2 + lh) ^ ((lj >> 1) & 3);  // == (j>>1)&3 swizzle
                    bf16x8 bf = *reinterpret_cast<const bf16x8*>(
                        &WsC[(size_t)j * 32 + c * 8]);
                    acc[mt] = __builtin_amdgcn_mfma_f32_32x32x16_bf16(
                        af[dt][kh], bf, acc[mt], 0, 0, 0);
                }
    };

    // prologue: fill buffer 0 for ks=0
    {
        float a16[16], a8[8];
        load_A(0, a16, a8);
        stage_W(&Ws[0], 0);
        write_A(&As[0], a16, a8);
        __syncthreads();
    }

    for (int ks = 0; ks < NKS; ++ks) {
        unsigned short* WsC = &Ws[(ks & 1) * WS_HALF];
        unsigned short* AsC = &As[(ks & 1) * AS_HALF];
        unsigned short* WsN = &Ws[((ks & 1) ^ 1) * WS_HALF];
        unsigned short* AsN = &As[((ks & 1) ^ 1) * AS_HALF];
        float a16[16], a8[8];
        const bool dn = (ks + 1 < NKS);
        if (dn) {
            load_A((ks + 1) * 32, a16, a8);   // issue early (regs)
            stage_W(WsN, (ks + 1) * 32);      // issue early (gload_lds)
        }
        compute(WsC, AsC);                    // loads land under MFMA
        if (dn) write_A(AsN, a16, a8);        // write late
        __syncthreads();                      // one barrier per step
    }

    // epilogue: normalized stores; every output owned by exactly one block
    #pragma unroll
    for (int mt = 0; mt < 5; ++mt) {
        #pragma unroll
        for (int rg = 0; rg < 16; ++rg) {
            int urow = (rg & 3) + 8 * (rg >> 2) + 4 * lh;
            int u  = u0 + w * 32 + urow;
            int m  = mt * 32 + lj;
            int pe = u * HOP + m;
            int po = pe - (NFFT / 2);
            if (po >= 0 && po < OUTLEN)
                out[(size_t)b * OUTLEN + po] = acc[mt][rg] * rssw[pe];
        }
    }
}

// ---------------- launcher ----------------
extern "C" void kernel_launch(void* const* d_in, const int* in_sizes, int n_in,
                              void* d_out, int out_size, void* d_ws, size_t ws_size,
                              hipStream_t stream) {
    const float* x = (const float*)d_in[0];
    float* out = (float*)d_out;

    unsigned short* Wt2 = (unsigned short*)d_ws;             // 399,360 B
    float* rssw = (float*)((char*)d_ws + 399360);            // ESTLEN floats

    {
        int total = JP * KP;
        build_wt2<<<(total + 255) / 256, 256, 0, stream>>>(Wt2);
    }
    {
        build_rssw<<<(ESTLEN + 255) / 256, 256, 0, stream>>>(rssw);
    }
    {
        dim3 grid(32, BB);                                   // 32*96 >= 3000 u-values
        istft_fused<<<grid, 192, 0, stream>>>(x, Wt2, rssw, out);
    }
}